// Round 5
// baseline (209.098 us; speedup 1.0000x reference)
//
#include <hip/hip_runtime.h>
#include <hip/hip_bf16.h>
#include <math.h>

#define E_N 50
#define D_N 100
#define H_N 100
#define XS_LDW 51   // words per xs row (102 halfwords): odd stride -> conflict-free

__device__ __forceinline__ float bf2f(unsigned int s16) {
    return __uint_as_float(s16 << 16);
}

__device__ __forceinline__ unsigned short f2bf(float f) {
    unsigned int u = __float_as_uint(f);
    unsigned int r = (u + 0x7FFFu + ((u >> 16) & 1u)) >> 16;  // RNE
    return (unsigned short)r;
}

template <bool F32>
__device__ __forceinline__ float ldx(const void* p, int i) {
    if (F32) return reinterpret_cast<const float*>(p)[i];
    return bf2f(reinterpret_cast<const unsigned short*>(p)[i]);
}

template <bool F32>
__device__ __forceinline__ float4 ld4(const void* p, long long i4) {
    if (F32) return reinterpret_cast<const float4*>(p)[i4];
    uint2 v = reinterpret_cast<const uint2*>(p)[i4];
    float4 f;
    f.x = bf2f(v.x & 0xFFFFu);
    f.y = bf2f(v.x >> 16);
    f.z = bf2f(v.y & 0xFFFFu);
    f.w = bf2f(v.y >> 16);
    return f;
}

// detector: even halfwords of emb decode sane iff data is bf16
__device__ __forceinline__ int detect_f32(const void* emb, int tid, int* flag_s) {
    if (tid < 64) {
        unsigned short hw = reinterpret_cast<const unsigned short*>(emb)[tid * 2];
        float v = bf2f(hw);
        float a = fabsf(v);
        int sane = (v == 0.f) || (a >= 1e-4f && a <= 8.0f);
        unsigned long long ball = __ballot(sane);
        if (tid == 0) *flag_s = (__popcll(ball) < 32) ? 1 : 0;
    }
    __syncthreads();
    return *flag_s;
}

// ================= K_qu: U[g] = Wk * (Wq^T x0 + bq)  (2 graphs / 256 thr) ======
template <bool F32>
__device__ __forceinline__ void qu_core(int g, int tt, int act,
    const int* __restrict__ nbr, const void* __restrict__ emb,
    const void* __restrict__ Wq, const void* __restrict__ bq,
    const void* __restrict__ Wk, float* __restrict__ U, float* q0s)
{
    int row = 0;
    if (act) row = __builtin_amdgcn_readfirstlane(nbr[g * E_N]);

    // q0[h] = bq[h] + sum_d x0[d] * Wq[d,h]   (Wq coalesced across lanes)
    if (act && tt < H_N) {
        float acc = ldx<F32>(bq, tt);
        #pragma unroll 10
        for (int d = 0; d < D_N; ++d)
            acc = fmaf(ldx<F32>(emb, row * D_N + d), ldx<F32>(Wq, d * H_N + tt), acc);
        q0s[tt] = acc;
    }
    __syncthreads();

    // u[d] = sum_h Wk[d,h] * q0[h]   (Wk row per lane, float4 over h)
    if (act && tt < D_N) {
        float acc = 0.f;
        #pragma unroll
        for (int hq = 0; hq < D_N / 4; ++hq) {
            float4 w = ld4<F32>(Wk, (long long)tt * (H_N / 4) + hq);
            const float4 q = reinterpret_cast<const float4*>(q0s)[hq];
            acc = fmaf(w.x, q.x, acc);
            acc = fmaf(w.y, q.y, acc);
            acc = fmaf(w.z, q.z, acc);
            acc = fmaf(w.w, q.w, acc);
        }
        U[(size_t)g * D_N + tt] = acc;
    }
}

__global__ __launch_bounds__(256)
void qu_kernel(const int* __restrict__ nbr, const void* __restrict__ emb,
               const void* __restrict__ Wq, const void* __restrict__ bq,
               const void* __restrict__ Wk, float* __restrict__ U, int G)
{
    __shared__ float q0s[2][H_N] __attribute__((aligned(16)));
    __shared__ int flag_s;
    const int t = threadIdx.x;
    const int sub = t >> 7, tt = t & 127;
    const int g = blockIdx.x * 2 + sub;
    const int act = (g < G);
    int f32 = detect_f32(emb, t, &flag_s);
    if (f32) qu_core<true>(g, tt, act, nbr, emb, Wq, bq, Wk, U, q0s[sub]);
    else     qu_core<false>(g, tt, act, nbr, emb, Wq, bq, Wk, U, q0s[sub]);
}

// ================= K_graph: gather + scores + softmax + y  (1 graph / wave) ====
template <bool F32>
__device__ __forceinline__ void graph_core(int g, int lane,
    const int* __restrict__ nbr, const int* __restrict__ adj,
    const void* __restrict__ emb, const float* __restrict__ U,
    float* __restrict__ Y,
    unsigned int* xw, int* ids, int* msk, float* us, float* ssc, float* attns)
{
    // independent loads first: mask + u (stay outstanding across gather setup)
    int mk = (lane < E_N) ? adj[(size_t)g * (E_N * E_N) + lane * E_N] : 0;
    float4 uv;
    if (lane < 25)
        uv = reinterpret_cast<const float4*>(U + (size_t)g * D_N)[lane];

    if (lane < E_N) ids[lane] = nbr[g * E_N + lane];
    __syncthreads();   // single wave: compiles to waitcnt only

    // gather batch A: 10 independent dwordx4 per lane
    float4 bufA[10];
    #pragma unroll
    for (int k = 0; k < 10; ++k) {
        int i = lane + 64 * k;                 // 0..639 < 1250
        int j = i / 25, q = i - j * 25;
        bufA[k] = ld4<F32>(emb, (long long)ids[j] * 25 + q);
    }
    // gather batch B
    float4 bufB[10];
    #pragma unroll
    for (int k = 0; k < 10; ++k) {
        int i = lane + 64 * (k + 10);
        if (i < E_N * 25) {
            int j = i / 25, q = i - j * 25;
            bufB[k] = ld4<F32>(emb, (long long)ids[j] * 25 + q);
        }
    }

    if (lane < E_N) msk[lane] = mk;
    if (lane < 25) reinterpret_cast<float4*>(us)[lane] = uv;

    // pack to bf16 LDS
    #pragma unroll
    for (int k = 0; k < 10; ++k) {
        int i = lane + 64 * k;
        int j = i / 25, q = i - j * 25;
        float4 f = bufA[k];
        xw[j * XS_LDW + 2 * q]     = (unsigned int)f2bf(f.x) | ((unsigned int)f2bf(f.y) << 16);
        xw[j * XS_LDW + 2 * q + 1] = (unsigned int)f2bf(f.z) | ((unsigned int)f2bf(f.w) << 16);
    }
    #pragma unroll
    for (int k = 0; k < 10; ++k) {
        int i = lane + 64 * (k + 10);
        if (i < E_N * 25) {
            int j = i / 25, q = i - j * 25;
            float4 f = bufB[k];
            xw[j * XS_LDW + 2 * q]     = (unsigned int)f2bf(f.x) | ((unsigned int)f2bf(f.y) << 16);
            xw[j * XS_LDW + 2 * q + 1] = (unsigned int)f2bf(f.z) | ((unsigned int)f2bf(f.w) << 16);
        }
    }
    __syncthreads();

    // scores s_j = 0.1 * (u . x_j)
    if (lane < E_N) {
        const unsigned int* xr = xw + lane * XS_LDW;
        float acc = 0.f;
        #pragma unroll 10
        for (int d2 = 0; d2 < D_N / 2; ++d2) {
            unsigned int w = xr[d2];
            acc = fmaf(bf2f(w & 0xFFFFu), us[2 * d2], acc);
            acc = fmaf(bf2f(w >> 16),     us[2 * d2 + 1], acc);
        }
        ssc[lane] = acc * 0.1f;
    }
    __syncthreads();

    // masked softmax numerators (msk[0]=1 via self-loop => den > 0 always)
    if (lane < E_N) {
        float m = -3.0e38f;
        #pragma unroll 10
        for (int j = 0; j < E_N; ++j)
            if (msk[j]) m = fmaxf(m, ssc[j]);
        attns[lane] = msk[lane] ? __expf(ssc[lane] - m) : 0.f;
    }
    __syncthreads();

    // y[d] = (sum_j e_j x[j,d]) / den ; write Y[g]
    {
        float den = 0.f;
        #pragma unroll 10
        for (int j = 0; j < E_N; ++j) den += attns[j];
        float inv = 1.0f / den;
        #pragma unroll
        for (int rep = 0; rep < 2; ++rep) {
            int d = lane + 64 * rep;
            if (d < D_N) {
                float acc = 0.f;
                #pragma unroll 10
                for (int j = 0; j < E_N; ++j) {
                    unsigned int w = xw[j * XS_LDW + (d >> 1)];
                    float xv = bf2f((d & 1) ? (w >> 16) : (w & 0xFFFFu));
                    acc = fmaf(attns[j], xv, acc);
                }
                Y[(size_t)g * D_N + d] = acc * inv;
            }
        }
    }
}

__global__ __launch_bounds__(64)
void graph_kernel(const int* __restrict__ nbr, const int* __restrict__ adj,
                  const void* __restrict__ emb, const float* __restrict__ U,
                  float* __restrict__ Y)
{
    __shared__ unsigned int xw[E_N * XS_LDW];
    __shared__ int   ids[E_N];
    __shared__ int   msk[E_N];
    __shared__ float us[D_N] __attribute__((aligned(16)));
    __shared__ float ssc[E_N];
    __shared__ float attns[E_N];
    __shared__ int   flag_s;

    const int lane = threadIdx.x;
    const int g = blockIdx.x;
    int f32 = detect_f32(emb, lane, &flag_s);
    if (f32) graph_core<true>(g, lane, nbr, adj, emb, U, Y, xw, ids, msk, us, ssc, attns);
    else     graph_core<false>(g, lane, nbr, adj, emb, U, Y, xw, ids, msk, us, ssc, attns);
}

// ================= K_out: out = bs + bv + y.Wv + x0.Ws  (2 graphs / 256 thr) ===
template <bool F32>
__device__ __forceinline__ void out_core(int g, int tt, int act,
    const int* __restrict__ nbr, const void* __restrict__ emb,
    const void* __restrict__ Wv, const void* __restrict__ Ws,
    const void* __restrict__ bv, const void* __restrict__ bs,
    const float* __restrict__ Y, void* __restrict__ out)
{
    if (!act) return;
    int row = __builtin_amdgcn_readfirstlane(nbr[g * E_N]);
    if (tt < H_N) {
        float acc = ldx<F32>(bs, tt) + ldx<F32>(bv, tt);
        const float* yg = Y + (size_t)g * D_N;
        #pragma unroll 10
        for (int d = 0; d < D_N; ++d) {
            acc = fmaf(yg[d],                        ldx<F32>(Wv, d * H_N + tt), acc);
            acc = fmaf(ldx<F32>(emb, row * D_N + d), ldx<F32>(Ws, d * H_N + tt), acc);
        }
        size_t o = (size_t)g * H_N + tt;
        if (F32) reinterpret_cast<float*>(out)[o] = acc;
        else     reinterpret_cast<unsigned short*>(out)[o] = f2bf(acc);
    }
}

__global__ __launch_bounds__(256)
void out_kernel(const int* __restrict__ nbr, const void* __restrict__ emb,
                const void* __restrict__ Wv, const void* __restrict__ Ws,
                const void* __restrict__ bv, const void* __restrict__ bs,
                const float* __restrict__ Y, void* __restrict__ out, int G)
{
    __shared__ int flag_s;
    const int t = threadIdx.x;
    const int sub = t >> 7, tt = t & 127;
    const int g = blockIdx.x * 2 + sub;
    const int act = (g < G);
    int f32 = detect_f32(emb, t, &flag_s);
    if (f32) out_core<true>(g, tt, act, nbr, emb, Wv, Ws, bv, bs, Y, out);
    else     out_core<false>(g, tt, act, nbr, emb, Wv, Ws, bv, bs, Y, out);
}

extern "C" void kernel_launch(void* const* d_in, const int* in_sizes, int n_in,
                              void* d_out, int out_size, void* d_ws, size_t ws_size,
                              hipStream_t stream) {
    const int* nbr = (const int*)d_in[0];
    const int* adj = (const int*)d_in[1];
    const void* emb = d_in[2];
    const void* Wq  = d_in[3];
    const void* bq  = d_in[4];
    const void* Wk  = d_in[5];
    // d_in[6] = bk: cancels inside softmax — unused
    const void* Wv  = d_in[7];
    const void* bv  = d_in[8];
    const void* Ws  = d_in[9];
    const void* bs  = d_in[10];

    const int G = in_sizes[0] / E_N;      // B*L = 3200
    float* U = (float*)d_ws;              // [G,100]
    float* Y = U + (size_t)G * D_N;       // [G,100]   (ws use: 2.56 MB)

    qu_kernel<<<(G + 1) / 2, 256, 0, stream>>>(nbr, emb, Wq, bq, Wk, U, G);
    graph_kernel<<<G, 64, 0, stream>>>(nbr, adj, emb, U, Y);
    out_kernel<<<(G + 1) / 2, 256, 0, stream>>>(nbr, emb, Wv, Ws, bv, bs, Y, d_out, G);
}